// Round 20
// baseline (291.704 us; speedup 1.0000x reference)
//
#include <hip/hip_runtime.h>
#include <hip/hip_bf16.h>

typedef __bf16 bf16x8 __attribute__((ext_vector_type(8)));
typedef float f32x4 __attribute__((ext_vector_type(4)));
typedef float f32x16 __attribute__((ext_vector_type(16)));
using BF = __hip_bfloat16;

constexpr int B_   = 2;
constexpr int S_   = 2048;
constexpr int NH_  = 16;
constexpr int HD_  = 128;
constexpr int HID_ = 2048;
constexpr int CKV_ = 512;
constexpr int CQ_  = 1024;
constexpr int RD_  = 64;
constexpr int M_   = B_ * S_;
constexpr int DQK_ = HD_ + RD_;

__device__ __forceinline__ f32x4 mfma16(bf16x8 a, bf16x8 b, f32x4 c) {
  return __builtin_amdgcn_mfma_f32_16x16x32_bf16(a, b, c, 0, 0, 0);
}
__device__ __forceinline__ f32x16 mfma32(bf16x8 a, bf16x8 b, f32x16 c) {
  return __builtin_amdgcn_mfma_f32_32x32x16_bf16(a, b, c, 0, 0, 0);
}
__device__ __forceinline__ unsigned cvtpk(float a, float b) {
  unsigned r;
  asm("v_cvt_pk_bf16_f32 %0, %1, %2" : "=v"(r) : "v"(a), "v"(b));
  return r;
}
__device__ __forceinline__ void gload16(const void* g, void* lds) {
  __builtin_amdgcn_global_load_lds((const __attribute__((address_space(1))) void*)g,
                                   (__attribute__((address_space(3))) void*)lds,
                                   16, 0, 0);
}
__device__ __forceinline__ void plswap(unsigned& x, unsigned& y, bool hi) {
#if __has_builtin(__builtin_amdgcn_permlane32_swap)
  typedef unsigned u32x2 __attribute__((ext_vector_type(2)));
  u32x2 r = __builtin_amdgcn_permlane32_swap(x, y, false, false);
  x = r[0];
  y = r[1];
#else
  unsigned sx = (unsigned)__shfl_xor((int)x, 32, 64);
  unsigned sy = (unsigned)__shfl_xor((int)y, 32, 64);
  unsigned nx = hi ? sy : x;
  unsigned ny = hi ? y : sx;
  x = nx;
  y = ny;
#endif
}

// ---------------- fp32 -> bf16 convert ----------------
__global__ __launch_bounds__(256) void f2b_kern(const float* __restrict__ in,
                                                BF* __restrict__ out, int n4) {
  int i = blockIdx.x * 256 + threadIdx.x;
  if (i >= n4) return;
  float4 v = reinterpret_cast<const float4*>(in)[i];
  BF o[4] = {__float2bfloat16(v.x), __float2bfloat16(v.y),
             __float2bfloat16(v.z), __float2bfloat16(v.w)};
  reinterpret_cast<uint2*>(out)[i] = *reinterpret_cast<uint2*>(o);
}

// ------------- all weight transposes in ONE launch -------
__global__ __launch_bounds__(256) void wtrans_all(const float* __restrict__ w0,
                                                  const float* __restrict__ w1,
                                                  const float* __restrict__ w2,
                                                  const float* __restrict__ w3,
                                                  const float* __restrict__ w4,
                                                  const float* __restrict__ w5,
                                                  const float* __restrict__ w6,
                                                  const float* __restrict__ w7,
                                                  BF* __restrict__ tCat1,
                                                  BF* __restrict__ tCat2,
                                                  BF* __restrict__ tCat3,
                                                  BF* __restrict__ tWO) {
  const int cum[9] = {0, 1024, 3072, 3328, 4352, 5376, 7424, 8448, 12544};
  const int nxt[8] = {16, 32, 4, 64, 64, 64, 32, 64};
  const int Kt[8]  = {2048, 2048, 2048, 512, 512, 1024, 1024, 2048};
  const int Nt[8]  = {512, 1024, 64, 2048, 2048, 2048, 1024, 2048};
  int bid = blockIdx.x;
  int j = 0;
#pragma unroll
  for (int t = 1; t < 8; t++)
    if (bid >= cum[t]) j = t;
  const float* in = (j == 0) ? w0 : (j == 1) ? w1 : (j == 2) ? w2 : (j == 3) ? w3
                   : (j == 4) ? w4 : (j == 5) ? w5 : (j == 6) ? w6 : w7;
  BF* out = (j == 0) ? tCat1 : (j == 1) ? tCat1 + (size_t)512 * 2048
           : (j == 2) ? tCat1 + (size_t)1536 * 2048
           : (j == 3) ? tCat2 : (j == 4) ? tCat2 + (size_t)2048 * 512
           : (j == 5) ? tCat3 : (j == 6) ? tCat3 + (size_t)2048 * 1024 : tWO;
  const int K = Kt[j], N = Nt[j];
  int rem = bid - cum[j];
  int bx = rem % nxt[j], by = rem / nxt[j];
  int n0 = bx * 32, k0 = by * 32;

  __shared__ float t[32][33];
  int tx = threadIdx.x, ty = threadIdx.y;
#pragma unroll
  for (int j4 = 0; j4 < 4; j4++) {
    int k = k0 + ty + j4 * 8, n = n0 + tx;
    t[ty + j4 * 8][tx] = (n < N) ? in[(size_t)k * N + n] : 0.f;
  }
  __syncthreads();
#pragma unroll
  for (int j4 = 0; j4 < 4; j4++) {
    int n = n0 + ty + j4 * 8, k = k0 + tx;
    out[(size_t)n * K + k] = __float2bfloat16(t[tx][ty + j4 * 8]);
  }
}

// ---------------- fused GEMM, 3-buffer counted-vmcnt (r13 geometry) -------------
template <int F>
__global__ __launch_bounds__(256) void gemm_f(const BF* __restrict__ A,
                                              const BF* __restrict__ Bt,
                                              void* __restrict__ C0,
                                              void* __restrict__ C1,
                                              void* __restrict__ C2,
                                              int M, int N, int K) {
  __shared__ BF As[3][128][32];
  __shared__ BF Bs[3][128][32];
  const int tid = threadIdx.x;
  const int w = tid >> 6, l = tid & 63;
  const int lr = l & 15, lg = l >> 4;
  const int wr = w >> 1, wc = w & 1;
  const int gx = gridDim.x;
  const int nwg = gx * gridDim.y;
  const int f = blockIdx.y * gx + blockIdx.x;
  const int swz = (f & 7) * (nwg >> 3) + (f >> 3);
  const int m0 = (swz / gx) * 128, n0 = (swz % gx) * 128;

  f32x4 acc[4][4];
#pragma unroll
  for (int m = 0; m < 4; m++)
#pragma unroll
    for (int n = 0; n < 4; n++) acc[m][n] = (f32x4){0.f, 0.f, 0.f, 0.f};

  auto STAGE = [&](int buf, int k0) {
#pragma unroll
    for (int j = 0; j < 2; j++) {
      int idx = tid + j * 256;
      int row = idx >> 2, seg = idx & 3;
      gload16(A + (size_t)(m0 + row) * K + k0 + seg * 8, &As[buf][0][0] + idx * 8);
      gload16(Bt + (size_t)(n0 + row) * K + k0 + seg * 8, &Bs[buf][0][0] + idx * 8);
    }
  };

  const int nk = K >> 5;
  STAGE(0, 0);
  if (nk > 1) STAGE(1, 32);
  asm volatile("s_waitcnt vmcnt(4)" ::: "memory");
  __builtin_amdgcn_sched_barrier(0);
  __builtin_amdgcn_s_barrier();

  int cur = 0;
  for (int ki = 0; ki < nk; ki++) {
    bf16x8 af[4], bfr[4];
#pragma unroll
    for (int m = 0; m < 4; m++)
      af[m] = *reinterpret_cast<const bf16x8*>(&As[cur][wr * 64 + m * 16 + lr][lg * 8]);
#pragma unroll
    for (int n = 0; n < 4; n++)
      bfr[n] = *reinterpret_cast<const bf16x8*>(&Bs[cur][wc * 64 + n * 16 + lr][lg * 8]);
    if (ki + 2 < nk) {
      int nb = cur + 2; if (nb >= 3) nb -= 3;
      STAGE(nb, (ki + 2) << 5);
    }
    __builtin_amdgcn_sched_barrier(0);
    __builtin_amdgcn_s_setprio(1);
#pragma unroll
    for (int m = 0; m < 4; m++)
#pragma unroll
      for (int n = 0; n < 4; n++) acc[m][n] = mfma16(af[m], bfr[n], acc[m][n]);
    __builtin_amdgcn_s_setprio(0);
    __builtin_amdgcn_sched_barrier(0);
    if (ki + 1 < nk) {
      if (ki + 2 < nk) {
        asm volatile("s_waitcnt vmcnt(4)" ::: "memory");
      } else {
        asm volatile("s_waitcnt vmcnt(0)" ::: "memory");
      }
      __builtin_amdgcn_sched_barrier(0);
      __builtin_amdgcn_s_barrier();
    }
    cur = cur + 1; if (cur >= 3) cur = 0;
  }

#pragma unroll
  for (int m = 0; m < 4; m++) {
#pragma unroll
    for (int n = 0; n < 4; n++) {
#pragma unroll
      for (int j = 0; j < 4; j++) {
        int row = m0 + wr * 64 + m * 16 + lg * 4 + j;
        int col = n0 + wc * 64 + n * 16 + lr;
        float v = acc[m][n][j];
        if constexpr (F == 1) {
          if (col < 512)
            ((BF*)C0)[(size_t)row * 512 + col] = __float2bfloat16(v);
          else if (col < 1536)
            ((BF*)C1)[(size_t)row * 1024 + (col - 512)] = __float2bfloat16(v);
          else
            ((BF*)C2)[(size_t)row * 128 + (col - 1536)] = __float2bfloat16(v);
        } else {
          ((float*)C0)[(size_t)row * 2048 + col] = v;
        }
      }
    }
  }
}

// ------- merged mid GEMMs + LDS-staged epilogue + fused RoPE-q -------
__global__ __launch_bounds__(256) void gemm_f23(const BF* __restrict__ cQ,
                                                const BF* __restrict__ t3,
                                                BF* __restrict__ qbuf,
                                                const BF* __restrict__ cKV,
                                                const BF* __restrict__ t2,
                                                BF* __restrict__ kbuf,
                                                BF* __restrict__ vTb) {
  __shared__ BF sm[3 * 128 * 32 * 2];  // 49152 B: As(3) | Bs(3); reused as C-stage
  BF* Asm = sm;
  BF* Bsm = sm + 3 * 128 * 32;
  const int tid = threadIdx.x;
  const int w = tid >> 6, l = tid & 63;
  const int lr = l & 15, lg = l >> 4;
  const int wr = w >> 1, wc = w & 1;
  const int f = blockIdx.y * 56 + blockIdx.x;
  const int swz = (f & 7) * (1792 >> 3) + (f >> 3);
  const int xt = swz % 56;
  const int m0 = (swz / 56) * 128;
  const bool isF3 = xt < 24;
  const BF* A  = isF3 ? cQ : cKV;
  const BF* Bt = isF3 ? t3 : t2;
  const int K  = isF3 ? 1024 : 512;
  const int n0 = (isF3 ? xt : xt - 24) * 128;

  f32x4 acc[4][4];
#pragma unroll
  for (int m = 0; m < 4; m++)
#pragma unroll
    for (int n = 0; n < 4; n++) acc[m][n] = (f32x4){0.f, 0.f, 0.f, 0.f};

  auto STAGE = [&](int buf, int k0) {
#pragma unroll
    for (int j = 0; j < 2; j++) {
      int idx = tid + j * 256;
      int row = idx >> 2, seg = idx & 3;
      gload16(A + (size_t)(m0 + row) * K + k0 + seg * 8, Asm + buf * 4096 + idx * 8);
      gload16(Bt + (size_t)(n0 + row) * K + k0 + seg * 8, Bsm + buf * 4096 + idx * 8);
    }
  };

  const int nk = K >> 5;
  STAGE(0, 0);
  STAGE(1, 32);
  asm volatile("s_waitcnt vmcnt(4)" ::: "memory");
  __builtin_amdgcn_sched_barrier(0);
  __builtin_amdgcn_s_barrier();

  int cur = 0;
  for (int ki = 0; ki < nk; ki++) {
    bf16x8 af[4], bfr[4];
#pragma unroll
    for (int m = 0; m < 4; m++)
      af[m] = *reinterpret_cast<const bf16x8*>(Asm + cur * 4096 + (wr * 64 + m * 16 + lr) * 32 + lg * 8);
#pragma unroll
    for (int n = 0; n < 4; n++)
      bfr[n] = *reinterpret_cast<const bf16x8*>(Bsm + cur * 4096 + (wc * 64 + n * 16 + lr) * 32 + lg * 8);
    if (ki + 2 < nk) {
      int nb = cur + 2; if (nb >= 3) nb -= 3;
      STAGE(nb, (ki + 2) << 5);
    }
    __builtin_amdgcn_sched_barrier(0);
    __builtin_amdgcn_s_setprio(1);
#pragma unroll
    for (int m = 0; m < 4; m++)
#pragma unroll
      for (int n = 0; n < 4; n++) acc[m][n] = mfma16(af[m], bfr[n], acc[m][n]);
    __builtin_amdgcn_s_setprio(0);
    __builtin_amdgcn_sched_barrier(0);
    if (ki + 1 < nk) {
      if (ki + 2 < nk) {
        asm volatile("s_waitcnt vmcnt(4)" ::: "memory");
      } else {
        asm volatile("s_waitcnt vmcnt(0)" ::: "memory");
      }
      __builtin_amdgcn_sched_barrier(0);
      __builtin_amdgcn_s_barrier();
    }
    cur = cur + 1; if (cur >= 3) cur = 0;
  }

  // ---- LDS-staged epilogue ----
  const bool TR = (!isF3) && (n0 >= 2048);
  __syncthreads();
  BF* Cs = sm;  // [128][132]
#pragma unroll
  for (int m = 0; m < 4; m++) {
#pragma unroll
    for (int n = 0; n < 4; n++) {
#pragma unroll
      for (int j = 0; j < 4; j++) {
        int r = wr * 64 + m * 16 + lg * 4 + j;
        int c = wc * 64 + n * 16 + lr;
        BF v = __float2bfloat16(acc[m][n][j]);
        if (TR) Cs[c * 132 + r] = v;
        else    Cs[r * 132 + c] = v;
      }
    }
  }
  __syncthreads();
  const int cb = tid & 15, rb = tid >> 4;
  const int b = m0 >> 11, s0 = m0 & 2047;
  if (isF3) {
    if (n0 < 2048) {
      int h = n0 >> 7;
#pragma unroll
      for (int pass = 0; pass < 8; pass++) {
        int r = rb + pass * 16;
        bf16x8 v = *reinterpret_cast<const bf16x8*>(&Cs[r * 132 + cb * 8]);
        *reinterpret_cast<bf16x8*>(qbuf + ((size_t)(b * 16 + h) * 2048 + s0 + r) * 192 + cb * 8) = v;
      }
    } else {  // q_R region: fused RoPE
      int cg0 = (n0 - 2048) + cb * 8;
      int h = cg0 >> 6;
      int d0 = cg0 & 63;
      bool lowh = (d0 & 32) == 0;
      float fr[8];
#pragma unroll
      for (int e = 0; e < 8; e++) {
        int di = (d0 & 31) + e;
        fr[e] = powf(10000.f, -(float)di / 32.0f);
      }
#pragma unroll
      for (int pass = 0; pass < 8; pass++) {
        int r = rb + pass * 16;
        int srow = s0 + r;
        bf16x8 xv = *reinterpret_cast<const bf16x8*>(&Cs[r * 132 + cb * 8]);
        bf16x8 pv = *reinterpret_cast<const bf16x8*>(&Cs[r * 132 + (cb ^ 4) * 8]);
        BF outv[8];
#pragma unroll
        for (int e = 0; e < 8; e++) {
          float x = (float)xv[e];
          float p = (float)pv[e];
          float rot = lowh ? -p : p;
          float ang = (float)srow * fr[e];
          outv[e] = __float2bfloat16(x * cosf(ang) + rot * sinf(ang));
        }
        *reinterpret_cast<bf16x8*>(qbuf + ((size_t)(b * 16 + h) * 2048 + srow) * 192 + 128 + d0) =
            *reinterpret_cast<bf16x8*>(outv);
      }
    }
  } else {
    if (n0 < 2048) {
      int h = n0 >> 7;
#pragma unroll
      for (int pass = 0; pass < 8; pass++) {
        int r = rb + pass * 16;
        bf16x8 v = *reinterpret_cast<const bf16x8*>(&Cs[r * 132 + cb * 8]);
        *reinterpret_cast<bf16x8*>(kbuf + ((size_t)(b * 16 + h) * 2048 + s0 + r) * 192 + cb * 8) = v;
      }
    } else {
      int h = (n0 - 2048) >> 7;
#pragma unroll
      for (int pass = 0; pass < 8; pass++) {
        int d = rb + pass * 16;
        bf16x8 v = *reinterpret_cast<const bf16x8*>(&Cs[d * 132 + cb * 8]);
        *reinterpret_cast<bf16x8*>(vTb + ((size_t)(b * 16 + h) * 128 + d) * 2048 + s0 + cb * 8) = v;
      }
    }
  }
}

// ---------------- RoPE for k, vectorized (bf16x8 loads/stores, head broadcast) ----------------
// grid: M_*8/256 = 128 blocks; thread = (m, d-chunk of 8)
__global__ __launch_bounds__(256) void rope_k(const BF* __restrict__ kr, BF* __restrict__ kb) {
  int idx = blockIdx.x * 256 + threadIdx.x;  // 4096*8
  int c8 = idx & 7, m = idx >> 3;
  int s = m & 2047, b = m >> 11;
  int d0 = c8 * 8;
  bool lowh = (d0 & 32) == 0;
  bf16x8 xv = *reinterpret_cast<const bf16x8*>(kr + (size_t)m * 128 + d0);
  bf16x8 pv = *reinterpret_cast<const bf16x8*>(kr + (size_t)m * 128 + (d0 ^ 32));
  BF outv[8];
#pragma unroll
  for (int e = 0; e < 8; e++) {
    int di = (d0 & 31) + e;
    float arg = (float)s * powf(10000.f, -(float)di / 32.0f);
    float x = (float)xv[e];
    float p = (float)pv[e];
    float rot = lowh ? -p : p;
    outv[e] = __float2bfloat16(x * cosf(arg) + rot * sinf(arg));
  }
  bf16x8 ov = *reinterpret_cast<bf16x8*>(outv);
#pragma unroll
  for (int h = 0; h < 16; h++)
    *reinterpret_cast<bf16x8*>(kb + ((size_t)(b * 16 + h) * 2048 + s) * 192 + 128 + d0) = ov;
}

// ---------------- flash attention (r18 config): pairing + setprio + dbuf
//                  + defer-max + tri-state mask ----------------
__global__ __launch_bounds__(256, 2) void attn_kern(const BF* __restrict__ qb,
                                                    const BF* __restrict__ kb,
                                                    const BF* __restrict__ vT,
                                                    BF* __restrict__ o) {
  const int yy = blockIdx.y;
  const bool second = yy >= 16;
  const int bh = second ? ((yy - 16) * 2 + 1) : (yy * 2);
  const int qt = second ? (int)blockIdx.x : (15 - (int)blockIdx.x);
  const int q0 = qt * 128;
  const int tid = threadIdx.x;
  const int w = tid >> 6, l = tid & 63;
  const int lo5 = l & 31;
  const int hi = l >> 5;
  const int l7 = l & 7;

  __shared__ __align__(16) char smem[81920];

  const int q = q0 + w * 32 + lo5;
  const int qmax = q0 + w * 32 + 31;
  const int qmin = q0 + w * 32;

  bf16x8 aq[12];
  {
    const BF* qrow = qb + ((size_t)bh * 2048 + q) * 192;
#pragma unroll
    for (int kst = 0; kst < 12; kst++)
      aq[kst] = *reinterpret_cast<const bf16x8*>(qrow + kst * 16 + hi * 8);
  }

  f32x16 Oacc[4];
#pragma unroll
  for (int dt = 0; dt < 4; dt++)
#pragma unroll
    for (int r = 0; r < 16; r++) Oacc[dt][r] = 0.f;
  float mrow = -3e38f, lrow = 0.f;

  const float scale = 0.07216878364870323f;
  const int nch = (q0 + 128) >> 6;

  auto STAGE = [&](int buf, int ch) {
    const int cc = ch << 6;
    BF* Ks = (BF*)(smem + buf * 40960);
    BF* Vs = (BF*)(smem + buf * 40960 + 24576);
#pragma unroll
    for (int j2 = 0; j2 < 6; j2++) {
      int D = tid + j2 * 256;
      int row = D / 24, sp = D % 24;
      int sl = sp ^ (row & 7);
      gload16(kb + ((size_t)bh * 2048 + cc + row) * 192 + sl * 8, Ks + D * 8);
    }
#pragma unroll
    for (int j2 = 0; j2 < 4; j2++) {
      int D = tid + j2 * 256;
      int row = D >> 3, sp = D & 7;
      int sl = sp ^ (row & 7);
      gload16(vT + ((size_t)bh * 128 + row) * 2048 + cc + sl * 8, Vs + D * 8);
    }
  };

  STAGE(0, 0);
  __syncthreads();

  for (int ch = 0; ch < nch; ch++) {
    const int c0 = ch << 6;
    const int cur = ch & 1;
    if (ch + 1 < nch) STAGE(cur ^ 1, ch + 1);
    __builtin_amdgcn_sched_barrier(0);
    BF* Ks = (BF*)(smem + cur * 40960);
    BF* Vs = (BF*)(smem + cur * 40960 + 24576);

    f32x16 sf[2];
    __builtin_amdgcn_s_setprio(1);
#pragma unroll
    for (int t = 0; t < 2; t++) {
      if (c0 + t * 32 <= qmax) {
        f32x16 a0, a1;
#pragma unroll
        for (int r = 0; r < 16; r++) { a0[r] = 0.f; a1[r] = 0.f; }
#pragma unroll
        for (int kst = 0; kst < 12; kst++) {
          bf16x8 kfr = *reinterpret_cast<const bf16x8*>(
              Ks + (t * 32 + lo5) * 192 + (((kst * 2 + hi) ^ l7) * 8));
          if (kst & 1) a1 = mfma32(kfr, aq[kst], a1);
          else         a0 = mfma32(kfr, aq[kst], a0);
        }
        sf[t] = a0 + a1;
      } else {
#pragma unroll
        for (int r = 0; r < 16; r++) sf[t][r] = 0.f;
      }
    }
    __builtin_amdgcn_s_setprio(0);

    // scale + mask: tri-state per 32-key tile
    float mx = -3e38f;
#pragma unroll
    for (int t = 0; t < 2; t++) {
      if (c0 + t * 32 > qmax) {
#pragma unroll
        for (int r = 0; r < 16; r++) sf[t][r] = -1e30f;
      } else if (c0 + t * 32 + 31 <= qmin) {
#pragma unroll
        for (int r = 0; r < 16; r++) {
          float v = sf[t][r] * scale;
          sf[t][r] = v;
          mx = fmaxf(mx, v);
        }
      } else {
#pragma unroll
        for (int r = 0; r < 16; r++) {
          int key = c0 + t * 32 + (r & 3) + 8 * (r >> 2) + 4 * hi;
          float v = sf[t][r] * scale;
          v = (key <= q) ? v : -1e30f;
          sf[t][r] = v;
          mx = fmaxf(mx, v);
        }
      }
    }
    mx = fmaxf(mx, __shfl_xor(mx, 32, 64));
    if (!__all(mx - mrow <= 8.0f)) {
      float mnew = fmaxf(mrow, mx);
      float corr = __expf(mrow - mnew);
      mrow = mnew;
      lrow *= corr;
#pragma unroll
      for (int dt = 0; dt < 4; dt++) Oacc[dt] *= corr;
    }
    float psum = 0.f;
#pragma unroll
    for (int t = 0; t < 2; t++)
#pragma unroll
      for (int r = 0; r < 16; r++) {
        float p = __expf(sf[t][r] - mrow);
        sf[t][r] = p;
        psum += p;
      }
    psum += __shfl_xor(psum, 32, 64);
    lrow += psum;

    bf16x8 pb[4];
#pragma unroll
    for (int ks = 0; ks < 4; ks++) {
      if (c0 + ks * 16 > qmax) continue;
      int t = ks >> 1, base = (ks & 1) * 8;
      unsigned Xa = cvtpk(sf[t][base + 0], sf[t][base + 1]);
      unsigned Xb = cvtpk(sf[t][base + 2], sf[t][base + 3]);
      unsigned Ya = cvtpk(sf[t][base + 4], sf[t][base + 5]);
      unsigned Yb = cvtpk(sf[t][base + 6], sf[t][base + 7]);
      plswap(Xa, Ya, hi != 0);
      plswap(Xb, Yb, hi != 0);
      union { unsigned u[4]; bf16x8 v; } pk_;
      pk_.u[0] = Xa; pk_.u[1] = Xb; pk_.u[2] = Ya; pk_.u[3] = Yb;
      pb[ks] = pk_.v;
    }

    __builtin_amdgcn_s_setprio(1);
#pragma unroll
    for (int ks = 0; ks < 4; ks++) {
      if (c0 + ks * 16 > qmax) continue;
#pragma unroll
      for (int dt = 0; dt < 4; dt++) {
        bf16x8 vfr = *reinterpret_cast<const bf16x8*>(
            Vs + (dt * 32 + lo5) * 64 + (((ks * 2 + hi) ^ l7) * 8));
        Oacc[dt] = mfma32(vfr, pb[ks], Oacc[dt]);
      }
    }
    __builtin_amdgcn_s_setprio(0);
    __syncthreads();
  }

  BF* Osh = (BF*)smem;
  float rinv = 1.0f / lrow;
  const int orow = w * 32 + lo5;
#pragma unroll
  for (int dt = 0; dt < 4; dt++) {
#pragma unroll
    for (int g = 0; g < 4; g++) {
      unsigned d0 = cvtpk(Oacc[dt][g * 4 + 0] * rinv, Oacc[dt][g * 4 + 1] * rinv);
      unsigned d1 = cvtpk(Oacc[dt][g * 4 + 2] * rinv, Oacc[dt][g * 4 + 3] * rinv);
      uint2 pr; pr.x = d0; pr.y = d1;
      *reinterpret_cast<uint2*>(Osh + orow * 136 + dt * 32 + g * 8 + hi * 4) = pr;
    }
  }
  __syncthreads();
  const int b = bh >> 4, h = bh & 15;
  const int cb = tid & 15, rb = tid >> 4;
#pragma unroll
  for (int rr = 0; rr < 8; rr++) {
    int row = rb + rr * 16;
    bf16x8 v = *reinterpret_cast<const bf16x8*>(Osh + row * 136 + cb * 8);
    *reinterpret_cast<bf16x8*>(o + ((size_t)(b * 2048 + q0 + row)) * 2048 + h * 128 + cb * 8) = v;
  }
}

extern "C" void kernel_launch(void* const* d_in, const int* in_sizes, int n_in,
                              void* d_out, int out_size, void* d_ws, size_t ws_size,
                              hipStream_t stream) {
  const float* hs   = (const float*)d_in[0];
  const float* wDKV = (const float*)d_in[2];
  const float* wUK  = (const float*)d_in[3];
  const float* wUV  = (const float*)d_in[4];
  const float* wDQ  = (const float*)d_in[5];
  const float* wUQ  = (const float*)d_in[6];
  const float* wQR  = (const float*)d_in[7];
  const float* wKR  = (const float*)d_in[8];
  const float* wO   = (const float*)d_in[9];
  float* out = (float*)d_out;

  char* ws = (char*)d_ws;
  size_t off = 0;
  auto alloc = [&](size_t bytes) -> char* {
    char* p = ws + off;
    off += (bytes + 255) & ~(size_t)255;
    return p;
  };
  BF* hsb   = (BF*)alloc((size_t)M_ * HID_ * 2);
  BF* tCat1 = (BF*)alloc((size_t)1664 * HID_ * 2);
  BF* tCat2 = (BF*)alloc((size_t)4096 * CKV_ * 2);
  BF* tCat3 = (BF*)alloc((size_t)3072 * CQ_ * 2);
  BF* tWO   = (BF*)alloc((size_t)HID_ * (NH_*HD_) * 2);
  BF* cKV   = (BF*)alloc((size_t)M_ * CKV_ * 2);
  BF* cQ    = (BF*)alloc((size_t)M_ * CQ_ * 2);
  BF* qbuf  = (BF*)alloc((size_t)B_ * NH_ * S_ * DQK_ * 2);
  BF* kbuf  = (BF*)alloc((size_t)B_ * NH_ * S_ * DQK_ * 2);
  BF* vTb   = (BF*)alloc((size_t)B_ * NH_ * HD_ * S_ * 2);
  BF* kRt   = (BF*)alloc((size_t)M_ * 128 * 2);
  BF* aout  = (BF*)alloc((size_t)M_ * (NH_*HD_) * 2);

  f2b_kern<<<(M_ * HID_ / 4 + 255) / 256, 256, 0, stream>>>(hs, hsb, M_ * HID_ / 4);

  wtrans_all<<<12544, dim3(32, 8), 0, stream>>>(wDKV, wDQ, wKR, wUK, wUV, wUQ, wQR, wO,
                                                tCat1, tCat2, tCat3, tWO);

  gemm_f<1><<<dim3(13, 32), 256, 0, stream>>>(hsb, tCat1, cKV, cQ, kRt, M_, 1664, HID_);
  gemm_f23<<<dim3(56, 32), 256, 0, stream>>>(cQ, tCat3, qbuf, cKV, tCat2, kbuf, vTb);

  rope_k<<<(M_ * 8) / 256, 256, 0, stream>>>(kRt, kbuf);

  attn_kern<<<dim3(S_ / 128, B_ * NH_), 256, 0, stream>>>(qbuf, kbuf, vTb, aout);

  gemm_f<4><<<dim3(16, 32), 256, 0, stream>>>(aout, tWO, out, nullptr, nullptr, M_, 2048, HID_);
}

// Round 21
// 270.133 us; speedup vs baseline: 1.0799x; 1.0799x over previous
//
#include <hip/hip_runtime.h>
#include <hip/hip_bf16.h>

typedef __bf16 bf16x8 __attribute__((ext_vector_type(8)));
typedef float f32x4 __attribute__((ext_vector_type(4)));
typedef float f32x16 __attribute__((ext_vector_type(16)));
using BF = __hip_bfloat16;

constexpr int B_   = 2;
constexpr int S_   = 2048;
constexpr int NH_  = 16;
constexpr int HD_  = 128;
constexpr int HID_ = 2048;
constexpr int CKV_ = 512;
constexpr int CQ_  = 1024;
constexpr int RD_  = 64;
constexpr int M_   = B_ * S_;
constexpr int DQK_ = HD_ + RD_;

__device__ __forceinline__ f32x4 mfma16(bf16x8 a, bf16x8 b, f32x4 c) {
  return __builtin_amdgcn_mfma_f32_16x16x32_bf16(a, b, c, 0, 0, 0);
}
__device__ __forceinline__ f32x16 mfma32(bf16x8 a, bf16x8 b, f32x16 c) {
  return __builtin_amdgcn_mfma_f32_32x32x16_bf16(a, b, c, 0, 0, 0);
}
__device__ __forceinline__ unsigned cvtpk(float a, float b) {
  unsigned r;
  asm("v_cvt_pk_bf16_f32 %0, %1, %2" : "=v"(r) : "v"(a), "v"(b));
  return r;
}
__device__ __forceinline__ void gload16(const void* g, void* lds) {
  __builtin_amdgcn_global_load_lds((const __attribute__((address_space(1))) void*)g,
                                   (__attribute__((address_space(3))) void*)lds,
                                   16, 0, 0);
}
__device__ __forceinline__ void plswap(unsigned& x, unsigned& y, bool hi) {
#if __has_builtin(__builtin_amdgcn_permlane32_swap)
  typedef unsigned u32x2 __attribute__((ext_vector_type(2)));
  u32x2 r = __builtin_amdgcn_permlane32_swap(x, y, false, false);
  x = r[0];
  y = r[1];
#else
  unsigned sx = (unsigned)__shfl_xor((int)x, 32, 64);
  unsigned sy = (unsigned)__shfl_xor((int)y, 32, 64);
  unsigned nx = hi ? sy : x;
  unsigned ny = hi ? y : sx;
  x = nx;
  y = ny;
#endif
}

// ---------------- fp32 -> bf16 convert ----------------
__global__ __launch_bounds__(256) void f2b_kern(const float* __restrict__ in,
                                                BF* __restrict__ out, int n4) {
  int i = blockIdx.x * 256 + threadIdx.x;
  if (i >= n4) return;
  float4 v = reinterpret_cast<const float4*>(in)[i];
  BF o[4] = {__float2bfloat16(v.x), __float2bfloat16(v.y),
             __float2bfloat16(v.z), __float2bfloat16(v.w)};
  reinterpret_cast<uint2*>(out)[i] = *reinterpret_cast<uint2*>(o);
}

// ------------- all weight transposes in ONE launch -------
__global__ __launch_bounds__(256) void wtrans_all(const float* __restrict__ w0,
                                                  const float* __restrict__ w1,
                                                  const float* __restrict__ w2,
                                                  const float* __restrict__ w3,
                                                  const float* __restrict__ w4,
                                                  const float* __restrict__ w5,
                                                  const float* __restrict__ w6,
                                                  const float* __restrict__ w7,
                                                  BF* __restrict__ tCat1,
                                                  BF* __restrict__ tCat2,
                                                  BF* __restrict__ tCat3,
                                                  BF* __restrict__ tWO) {
  const int cum[9] = {0, 1024, 3072, 3328, 4352, 5376, 7424, 8448, 12544};
  const int nxt[8] = {16, 32, 4, 64, 64, 64, 32, 64};
  const int Kt[8]  = {2048, 2048, 2048, 512, 512, 1024, 1024, 2048};
  const int Nt[8]  = {512, 1024, 64, 2048, 2048, 2048, 1024, 2048};
  int bid = blockIdx.x;
  int j = 0;
#pragma unroll
  for (int t = 1; t < 8; t++)
    if (bid >= cum[t]) j = t;
  const float* in = (j == 0) ? w0 : (j == 1) ? w1 : (j == 2) ? w2 : (j == 3) ? w3
                   : (j == 4) ? w4 : (j == 5) ? w5 : (j == 6) ? w6 : w7;
  BF* out = (j == 0) ? tCat1 : (j == 1) ? tCat1 + (size_t)512 * 2048
           : (j == 2) ? tCat1 + (size_t)1536 * 2048
           : (j == 3) ? tCat2 : (j == 4) ? tCat2 + (size_t)2048 * 512
           : (j == 5) ? tCat3 : (j == 6) ? tCat3 + (size_t)2048 * 1024 : tWO;
  const int K = Kt[j], N = Nt[j];
  int rem = bid - cum[j];
  int bx = rem % nxt[j], by = rem / nxt[j];
  int n0 = bx * 32, k0 = by * 32;

  __shared__ float t[32][33];
  int tx = threadIdx.x, ty = threadIdx.y;
#pragma unroll
  for (int j4 = 0; j4 < 4; j4++) {
    int k = k0 + ty + j4 * 8, n = n0 + tx;
    t[ty + j4 * 8][tx] = (n < N) ? in[(size_t)k * N + n] : 0.f;
  }
  __syncthreads();
#pragma unroll
  for (int j4 = 0; j4 < 4; j4++) {
    int n = n0 + ty + j4 * 8, k = k0 + tx;
    out[(size_t)n * K + k] = __float2bfloat16(t[tx][ty + j4 * 8]);
  }
}

// ---------------- fused GEMM, 3-buffer counted-vmcnt (r13 geometry) -------------
template <int F>
__global__ __launch_bounds__(256) void gemm_f(const BF* __restrict__ A,
                                              const BF* __restrict__ Bt,
                                              void* __restrict__ C0,
                                              void* __restrict__ C1,
                                              void* __restrict__ C2,
                                              int M, int N, int K) {
  __shared__ BF As[3][128][32];
  __shared__ BF Bs[3][128][32];
  const int tid = threadIdx.x;
  const int w = tid >> 6, l = tid & 63;
  const int lr = l & 15, lg = l >> 4;
  const int wr = w >> 1, wc = w & 1;
  const int gx = gridDim.x;
  const int nwg = gx * gridDim.y;
  const int f = blockIdx.y * gx + blockIdx.x;
  const int swz = (f & 7) * (nwg >> 3) + (f >> 3);
  const int m0 = (swz / gx) * 128, n0 = (swz % gx) * 128;

  f32x4 acc[4][4];
#pragma unroll
  for (int m = 0; m < 4; m++)
#pragma unroll
    for (int n = 0; n < 4; n++) acc[m][n] = (f32x4){0.f, 0.f, 0.f, 0.f};

  auto STAGE = [&](int buf, int k0) {
#pragma unroll
    for (int j = 0; j < 2; j++) {
      int idx = tid + j * 256;
      int row = idx >> 2, seg = idx & 3;
      gload16(A + (size_t)(m0 + row) * K + k0 + seg * 8, &As[buf][0][0] + idx * 8);
      gload16(Bt + (size_t)(n0 + row) * K + k0 + seg * 8, &Bs[buf][0][0] + idx * 8);
    }
  };

  const int nk = K >> 5;
  STAGE(0, 0);
  if (nk > 1) STAGE(1, 32);
  asm volatile("s_waitcnt vmcnt(4)" ::: "memory");
  __builtin_amdgcn_sched_barrier(0);
  __builtin_amdgcn_s_barrier();

  int cur = 0;
  for (int ki = 0; ki < nk; ki++) {
    bf16x8 af[4], bfr[4];
#pragma unroll
    for (int m = 0; m < 4; m++)
      af[m] = *reinterpret_cast<const bf16x8*>(&As[cur][wr * 64 + m * 16 + lr][lg * 8]);
#pragma unroll
    for (int n = 0; n < 4; n++)
      bfr[n] = *reinterpret_cast<const bf16x8*>(&Bs[cur][wc * 64 + n * 16 + lr][lg * 8]);
    if (ki + 2 < nk) {
      int nb = cur + 2; if (nb >= 3) nb -= 3;
      STAGE(nb, (ki + 2) << 5);
    }
    __builtin_amdgcn_sched_barrier(0);
    __builtin_amdgcn_s_setprio(1);
#pragma unroll
    for (int m = 0; m < 4; m++)
#pragma unroll
      for (int n = 0; n < 4; n++) acc[m][n] = mfma16(af[m], bfr[n], acc[m][n]);
    __builtin_amdgcn_s_setprio(0);
    __builtin_amdgcn_sched_barrier(0);
    if (ki + 1 < nk) {
      if (ki + 2 < nk) {
        asm volatile("s_waitcnt vmcnt(4)" ::: "memory");
      } else {
        asm volatile("s_waitcnt vmcnt(0)" ::: "memory");
      }
      __builtin_amdgcn_sched_barrier(0);
      __builtin_amdgcn_s_barrier();
    }
    cur = cur + 1; if (cur >= 3) cur = 0;
  }

#pragma unroll
  for (int m = 0; m < 4; m++) {
#pragma unroll
    for (int n = 0; n < 4; n++) {
#pragma unroll
      for (int j = 0; j < 4; j++) {
        int row = m0 + wr * 64 + m * 16 + lg * 4 + j;
        int col = n0 + wc * 64 + n * 16 + lr;
        float v = acc[m][n][j];
        if constexpr (F == 1) {
          if (col < 512)
            ((BF*)C0)[(size_t)row * 512 + col] = __float2bfloat16(v);
          else if (col < 1536)
            ((BF*)C1)[(size_t)row * 1024 + (col - 512)] = __float2bfloat16(v);
          else
            ((BF*)C2)[(size_t)row * 128 + (col - 1536)] = __float2bfloat16(v);
        } else {
          ((float*)C0)[(size_t)row * 2048 + col] = v;
        }
      }
    }
  }
}

// ------- merged mid GEMMs + LDS-staged epilogue + fused RoPE-q -------
__global__ __launch_bounds__(256) void gemm_f23(const BF* __restrict__ cQ,
                                                const BF* __restrict__ t3,
                                                BF* __restrict__ qbuf,
                                                const BF* __restrict__ cKV,
                                                const BF* __restrict__ t2,
                                                BF* __restrict__ kbuf,
                                                BF* __restrict__ vTb) {
  __shared__ BF sm[3 * 128 * 32 * 2];  // 49152 B: As(3) | Bs(3); reused as C-stage
  BF* Asm = sm;
  BF* Bsm = sm + 3 * 128 * 32;
  const int tid = threadIdx.x;
  const int w = tid >> 6, l = tid & 63;
  const int lr = l & 15, lg = l >> 4;
  const int wr = w >> 1, wc = w & 1;
  const int f = blockIdx.y * 56 + blockIdx.x;
  const int swz = (f & 7) * (1792 >> 3) + (f >> 3);
  const int xt = swz % 56;
  const int m0 = (swz / 56) * 128;
  const bool isF3 = xt < 24;
  const BF* A  = isF3 ? cQ : cKV;
  const BF* Bt = isF3 ? t3 : t2;
  const int K  = isF3 ? 1024 : 512;
  const int n0 = (isF3 ? xt : xt - 24) * 128;

  f32x4 acc[4][4];
#pragma unroll
  for (int m = 0; m < 4; m++)
#pragma unroll
    for (int n = 0; n < 4; n++) acc[m][n] = (f32x4){0.f, 0.f, 0.f, 0.f};

  auto STAGE = [&](int buf, int k0) {
#pragma unroll
    for (int j = 0; j < 2; j++) {
      int idx = tid + j * 256;
      int row = idx >> 2, seg = idx & 3;
      gload16(A + (size_t)(m0 + row) * K + k0 + seg * 8, Asm + buf * 4096 + idx * 8);
      gload16(Bt + (size_t)(n0 + row) * K + k0 + seg * 8, Bsm + buf * 4096 + idx * 8);
    }
  };

  const int nk = K >> 5;
  STAGE(0, 0);
  STAGE(1, 32);
  asm volatile("s_waitcnt vmcnt(4)" ::: "memory");
  __builtin_amdgcn_sched_barrier(0);
  __builtin_amdgcn_s_barrier();

  int cur = 0;
  for (int ki = 0; ki < nk; ki++) {
    bf16x8 af[4], bfr[4];
#pragma unroll
    for (int m = 0; m < 4; m++)
      af[m] = *reinterpret_cast<const bf16x8*>(Asm + cur * 4096 + (wr * 64 + m * 16 + lr) * 32 + lg * 8);
#pragma unroll
    for (int n = 0; n < 4; n++)
      bfr[n] = *reinterpret_cast<const bf16x8*>(Bsm + cur * 4096 + (wc * 64 + n * 16 + lr) * 32 + lg * 8);
    if (ki + 2 < nk) {
      int nb = cur + 2; if (nb >= 3) nb -= 3;
      STAGE(nb, (ki + 2) << 5);
    }
    __builtin_amdgcn_sched_barrier(0);
    __builtin_amdgcn_s_setprio(1);
#pragma unroll
    for (int m = 0; m < 4; m++)
#pragma unroll
      for (int n = 0; n < 4; n++) acc[m][n] = mfma16(af[m], bfr[n], acc[m][n]);
    __builtin_amdgcn_s_setprio(0);
    __builtin_amdgcn_sched_barrier(0);
    if (ki + 1 < nk) {
      if (ki + 2 < nk) {
        asm volatile("s_waitcnt vmcnt(4)" ::: "memory");
      } else {
        asm volatile("s_waitcnt vmcnt(0)" ::: "memory");
      }
      __builtin_amdgcn_sched_barrier(0);
      __builtin_amdgcn_s_barrier();
    }
    cur = cur + 1; if (cur >= 3) cur = 0;
  }

  // ---- LDS-staged epilogue ----
  const bool TR = (!isF3) && (n0 >= 2048);
  __syncthreads();
  BF* Cs = sm;  // [128][132]
#pragma unroll
  for (int m = 0; m < 4; m++) {
#pragma unroll
    for (int n = 0; n < 4; n++) {
#pragma unroll
      for (int j = 0; j < 4; j++) {
        int r = wr * 64 + m * 16 + lg * 4 + j;
        int c = wc * 64 + n * 16 + lr;
        BF v = __float2bfloat16(acc[m][n][j]);
        if (TR) Cs[c * 132 + r] = v;
        else    Cs[r * 132 + c] = v;
      }
    }
  }
  __syncthreads();
  const int cb = tid & 15, rb = tid >> 4;
  const int b = m0 >> 11, s0 = m0 & 2047;
  if (isF3) {
    if (n0 < 2048) {
      int h = n0 >> 7;
#pragma unroll
      for (int pass = 0; pass < 8; pass++) {
        int r = rb + pass * 16;
        bf16x8 v = *reinterpret_cast<const bf16x8*>(&Cs[r * 132 + cb * 8]);
        *reinterpret_cast<bf16x8*>(qbuf + ((size_t)(b * 16 + h) * 2048 + s0 + r) * 192 + cb * 8) = v;
      }
    } else {  // q_R region: fused RoPE
      int cg0 = (n0 - 2048) + cb * 8;
      int h = cg0 >> 6;
      int d0 = cg0 & 63;
      bool lowh = (d0 & 32) == 0;
      float fr[8];
#pragma unroll
      for (int e = 0; e < 8; e++) {
        int di = (d0 & 31) + e;
        fr[e] = powf(10000.f, -(float)di / 32.0f);
      }
#pragma unroll
      for (int pass = 0; pass < 8; pass++) {
        int r = rb + pass * 16;
        int srow = s0 + r;
        bf16x8 xv = *reinterpret_cast<const bf16x8*>(&Cs[r * 132 + cb * 8]);
        bf16x8 pv = *reinterpret_cast<const bf16x8*>(&Cs[r * 132 + (cb ^ 4) * 8]);
        BF outv[8];
#pragma unroll
        for (int e = 0; e < 8; e++) {
          float x = (float)xv[e];
          float p = (float)pv[e];
          float rot = lowh ? -p : p;
          float ang = (float)srow * fr[e];
          outv[e] = __float2bfloat16(x * cosf(ang) + rot * sinf(ang));
        }
        *reinterpret_cast<bf16x8*>(qbuf + ((size_t)(b * 16 + h) * 2048 + srow) * 192 + 128 + d0) =
            *reinterpret_cast<bf16x8*>(outv);
      }
    }
  } else {
    if (n0 < 2048) {
      int h = n0 >> 7;
#pragma unroll
      for (int pass = 0; pass < 8; pass++) {
        int r = rb + pass * 16;
        bf16x8 v = *reinterpret_cast<const bf16x8*>(&Cs[r * 132 + cb * 8]);
        *reinterpret_cast<bf16x8*>(kbuf + ((size_t)(b * 16 + h) * 2048 + s0 + r) * 192 + cb * 8) = v;
      }
    } else {
      int h = (n0 - 2048) >> 7;
#pragma unroll
      for (int pass = 0; pass < 8; pass++) {
        int d = rb + pass * 16;
        bf16x8 v = *reinterpret_cast<const bf16x8*>(&Cs[d * 132 + cb * 8]);
        *reinterpret_cast<bf16x8*>(vTb + ((size_t)(b * 16 + h) * 128 + d) * 2048 + s0 + cb * 8) = v;
      }
    }
  }
}

// ---------------- RoPE for k (broadcast to heads) ----------------
__global__ __launch_bounds__(256) void rope_k(const BF* __restrict__ kr, BF* __restrict__ kb) {
  int idx = blockIdx.x * 256 + threadIdx.x;
  int d = idx & 63, m = idx >> 6;
  int s = m & 2047, b = m >> 11;
  float x = __bfloat162float(kr[(size_t)m * 128 + d]);
  float other = __bfloat162float(kr[(size_t)m * 128 + (d ^ 32)]);
  float rot = (d < 32) ? -other : other;
  int di = d & 31;
  float arg = (float)s * powf(10000.f, -(float)di / 32.0f);
  float val = x * cosf(arg) + rot * sinf(arg);
  BF v = __float2bfloat16(val);
#pragma unroll
  for (int h = 0; h < 16; h++)
    kb[((size_t)(b * 16 + h) * 2048 + s) * 192 + 128 + d] = v;
}

// ---------------- flash attention (r18 config): pairing + setprio + dbuf
//                  + defer-max + tri-state mask (register-neutral) ----------------
__global__ __launch_bounds__(256, 2) void attn_kern(const BF* __restrict__ qb,
                                                    const BF* __restrict__ kb,
                                                    const BF* __restrict__ vT,
                                                    BF* __restrict__ o) {
  const int yy = blockIdx.y;
  const bool second = yy >= 16;
  const int bh = second ? ((yy - 16) * 2 + 1) : (yy * 2);
  const int qt = second ? (int)blockIdx.x : (15 - (int)blockIdx.x);
  const int q0 = qt * 128;
  const int tid = threadIdx.x;
  const int w = tid >> 6, l = tid & 63;
  const int lo5 = l & 31;
  const int hi = l >> 5;
  const int l7 = l & 7;

  __shared__ __align__(16) char smem[81920];

  const int q = q0 + w * 32 + lo5;
  const int qmax = q0 + w * 32 + 31;
  const int qmin = q0 + w * 32;

  bf16x8 aq[12];
  {
    const BF* qrow = qb + ((size_t)bh * 2048 + q) * 192;
#pragma unroll
    for (int kst = 0; kst < 12; kst++)
      aq[kst] = *reinterpret_cast<const bf16x8*>(qrow + kst * 16 + hi * 8);
  }

  f32x16 Oacc[4];
#pragma unroll
  for (int dt = 0; dt < 4; dt++)
#pragma unroll
    for (int r = 0; r < 16; r++) Oacc[dt][r] = 0.f;
  float mrow = -3e38f, lrow = 0.f;

  const float scale = 0.07216878364870323f;
  const int nch = (q0 + 128) >> 6;

  auto STAGE = [&](int buf, int ch) {
    const int cc = ch << 6;
    BF* Ks = (BF*)(smem + buf * 40960);
    BF* Vs = (BF*)(smem + buf * 40960 + 24576);
#pragma unroll
    for (int j2 = 0; j2 < 6; j2++) {
      int D = tid + j2 * 256;
      int row = D / 24, sp = D % 24;
      int sl = sp ^ (row & 7);
      gload16(kb + ((size_t)bh * 2048 + cc + row) * 192 + sl * 8, Ks + D * 8);
    }
#pragma unroll
    for (int j2 = 0; j2 < 4; j2++) {
      int D = tid + j2 * 256;
      int row = D >> 3, sp = D & 7;
      int sl = sp ^ (row & 7);
      gload16(vT + ((size_t)bh * 128 + row) * 2048 + cc + sl * 8, Vs + D * 8);
    }
  };

  STAGE(0, 0);
  __syncthreads();

  for (int ch = 0; ch < nch; ch++) {
    const int c0 = ch << 6;
    const int cur = ch & 1;
    if (ch + 1 < nch) STAGE(cur ^ 1, ch + 1);
    __builtin_amdgcn_sched_barrier(0);
    BF* Ks = (BF*)(smem + cur * 40960);
    BF* Vs = (BF*)(smem + cur * 40960 + 24576);

    f32x16 sf[2];
    __builtin_amdgcn_s_setprio(1);
#pragma unroll
    for (int t = 0; t < 2; t++) {
      if (c0 + t * 32 <= qmax) {
        f32x16 a0, a1;
#pragma unroll
        for (int r = 0; r < 16; r++) { a0[r] = 0.f; a1[r] = 0.f; }
#pragma unroll
        for (int kst = 0; kst < 12; kst++) {
          bf16x8 kfr = *reinterpret_cast<const bf16x8*>(
              Ks + (t * 32 + lo5) * 192 + (((kst * 2 + hi) ^ l7) * 8));
          if (kst & 1) a1 = mfma32(kfr, aq[kst], a1);
          else         a0 = mfma32(kfr, aq[kst], a0);
        }
        sf[t] = a0 + a1;
      } else {
#pragma unroll
        for (int r = 0; r < 16; r++) sf[t][r] = 0.f;
      }
    }
    __builtin_amdgcn_s_setprio(0);

    // scale + mask: tri-state per 32-key tile
    float mx = -3e38f;
#pragma unroll
    for (int t = 0; t < 2; t++) {
      if (c0 + t * 32 > qmax) {
#pragma unroll
        for (int r = 0; r < 16; r++) sf[t][r] = -1e30f;
      } else if (c0 + t * 32 + 31 <= qmin) {
#pragma unroll
        for (int r = 0; r < 16; r++) {
          float v = sf[t][r] * scale;
          sf[t][r] = v;
          mx = fmaxf(mx, v);
        }
      } else {
#pragma unroll
        for (int r = 0; r < 16; r++) {
          int key = c0 + t * 32 + (r & 3) + 8 * (r >> 2) + 4 * hi;
          float v = sf[t][r] * scale;
          v = (key <= q) ? v : -1e30f;
          sf[t][r] = v;
          mx = fmaxf(mx, v);
        }
      }
    }
    mx = fmaxf(mx, __shfl_xor(mx, 32, 64));
    if (!__all(mx - mrow <= 8.0f)) {
      float mnew = fmaxf(mrow, mx);
      float corr = __expf(mrow - mnew);
      mrow = mnew;
      lrow *= corr;
#pragma unroll
      for (int dt = 0; dt < 4; dt++) Oacc[dt] *= corr;
    }
    float psum = 0.f;
#pragma unroll
    for (int t = 0; t < 2; t++)
#pragma unroll
      for (int r = 0; r < 16; r++) {
        float p = __expf(sf[t][r] - mrow);
        sf[t][r] = p;
        psum += p;
      }
    psum += __shfl_xor(psum, 32, 64);
    lrow += psum;

    bf16x8 pb[4];
#pragma unroll
    for (int ks = 0; ks < 4; ks++) {
      if (c0 + ks * 16 > qmax) continue;
      int t = ks >> 1, base = (ks & 1) * 8;
      unsigned Xa = cvtpk(sf[t][base + 0], sf[t][base + 1]);
      unsigned Xb = cvtpk(sf[t][base + 2], sf[t][base + 3]);
      unsigned Ya = cvtpk(sf[t][base + 4], sf[t][base + 5]);
      unsigned Yb = cvtpk(sf[t][base + 6], sf[t][base + 7]);
      plswap(Xa, Ya, hi != 0);
      plswap(Xb, Yb, hi != 0);
      union { unsigned u[4]; bf16x8 v; } pk_;
      pk_.u[0] = Xa; pk_.u[1] = Xb; pk_.u[2] = Ya; pk_.u[3] = Yb;
      pb[ks] = pk_.v;
    }

    __builtin_amdgcn_s_setprio(1);
#pragma unroll
    for (int ks = 0; ks < 4; ks++) {
      if (c0 + ks * 16 > qmax) continue;
#pragma unroll
      for (int dt = 0; dt < 4; dt++) {
        bf16x8 vfr = *reinterpret_cast<const bf16x8*>(
            Vs + (dt * 32 + lo5) * 64 + (((ks * 2 + hi) ^ l7) * 8));
        Oacc[dt] = mfma32(vfr, pb[ks], Oacc[dt]);
      }
    }
    __builtin_amdgcn_s_setprio(0);
    __syncthreads();
  }

  BF* Osh = (BF*)smem;
  float rinv = 1.0f / lrow;
  const int orow = w * 32 + lo5;
#pragma unroll
  for (int dt = 0; dt < 4; dt++) {
#pragma unroll
    for (int g = 0; g < 4; g++) {
      unsigned d0 = cvtpk(Oacc[dt][g * 4 + 0] * rinv, Oacc[dt][g * 4 + 1] * rinv);
      unsigned d1 = cvtpk(Oacc[dt][g * 4 + 2] * rinv, Oacc[dt][g * 4 + 3] * rinv);
      uint2 pr; pr.x = d0; pr.y = d1;
      *reinterpret_cast<uint2*>(Osh + orow * 136 + dt * 32 + g * 8 + hi * 4) = pr;
    }
  }
  __syncthreads();
  const int b = bh >> 4, h = bh & 15;
  const int cb = tid & 15, rb = tid >> 4;
#pragma unroll
  for (int rr = 0; rr < 8; rr++) {
    int row = rb + rr * 16;
    bf16x8 v = *reinterpret_cast<const bf16x8*>(Osh + row * 136 + cb * 8);
    *reinterpret_cast<bf16x8*>(o + ((size_t)(b * 2048 + q0 + row)) * 2048 + h * 128 + cb * 8) = v;
  }
}

extern "C" void kernel_launch(void* const* d_in, const int* in_sizes, int n_in,
                              void* d_out, int out_size, void* d_ws, size_t ws_size,
                              hipStream_t stream) {
  const float* hs   = (const float*)d_in[0];
  const float* wDKV = (const float*)d_in[2];
  const float* wUK  = (const float*)d_in[3];
  const float* wUV  = (const float*)d_in[4];
  const float* wDQ  = (const float*)d_in[5];
  const float* wUQ  = (const float*)d_in[6];
  const float* wQR  = (const float*)d_in[7];
  const float* wKR  = (const float*)d_in[8];
  const float* wO   = (const float*)d_in[9];
  float* out = (float*)d_out;

  char* ws = (char*)d_ws;
  size_t off = 0;
  auto alloc = [&](size_t bytes) -> char* {
    char* p = ws + off;
    off += (bytes + 255) & ~(size_t)255;
    return p;
  };
  BF* hsb   = (BF*)alloc((size_t)M_ * HID_ * 2);
  BF* tCat1 = (BF*)alloc((size_t)1664 * HID_ * 2);
  BF* tCat2 = (BF*)alloc((size_t)4096 * CKV_ * 2);
  BF* tCat3 = (BF*)alloc((size_t)3072 * CQ_ * 2);
  BF* tWO   = (BF*)alloc((size_t)HID_ * (NH_*HD_) * 2);
  BF* cKV   = (BF*)alloc((size_t)M_ * CKV_ * 2);
  BF* cQ    = (BF*)alloc((size_t)M_ * CQ_ * 2);
  BF* qbuf  = (BF*)alloc((size_t)B_ * NH_ * S_ * DQK_ * 2);
  BF* kbuf  = (BF*)alloc((size_t)B_ * NH_ * S_ * DQK_ * 2);
  BF* vTb   = (BF*)alloc((size_t)B_ * NH_ * HD_ * S_ * 2);
  BF* kRt   = (BF*)alloc((size_t)M_ * 128 * 2);
  BF* aout  = (BF*)alloc((size_t)M_ * (NH_*HD_) * 2);

  f2b_kern<<<(M_ * HID_ / 4 + 255) / 256, 256, 0, stream>>>(hs, hsb, M_ * HID_ / 4);

  wtrans_all<<<12544, dim3(32, 8), 0, stream>>>(wDKV, wDQ, wKR, wUK, wUV, wUQ, wQR, wO,
                                                tCat1, tCat2, tCat3, tWO);

  gemm_f<1><<<dim3(13, 32), 256, 0, stream>>>(hsb, tCat1, cKV, cQ, kRt, M_, 1664, HID_);
  gemm_f23<<<dim3(56, 32), 256, 0, stream>>>(cQ, tCat3, qbuf, cKV, tCat2, kbuf, vTb);

  rope_k<<<(M_ * RD_) / 256, 256, 0, stream>>>(kRt, kbuf);

  attn_kern<<<dim3(S_ / 128, B_ * NH_), 256, 0, stream>>>(qbuf, kbuf, vTb, aout);

  gemm_f<4><<<dim3(16, 32), 256, 0, stream>>>(aout, tWO, out, nullptr, nullptr, M_, 2048, HID_);
}